// Round 1
// baseline (284.560 us; speedup 1.0000x reference)
//
#include <hip/hip_runtime.h>
#include <hip/hip_bf16.h>
#include <math.h>

// ---------------------------------------------------------------------------
// Workspace layout (float offsets)
// ---------------------------------------------------------------------------
constexpr size_t OFF_QW1  = 0;
constexpr size_t OFF_QW2  = OFF_QW1 + 162;
constexpr size_t OFF_QB2  = OFF_QW2 + 648;
constexpr size_t OFF_QW3  = OFF_QB2 + 12;
constexpr size_t OFF_QB3  = OFF_QW3 + 1944;
constexpr size_t OFF_QW4  = OFF_QB3 + 18;
constexpr size_t OFF_QB4  = OFF_QW4 + 2916;
constexpr size_t OFF_QW5  = OFF_QB4 + 18;
constexpr size_t OFF_QB5  = OFF_QW5 + 2916;
constexpr size_t OFF_QF1  = OFF_QB5 + 18;
constexpr size_t OFF_QFB1 = OFF_QF1 + 19440;
constexpr size_t OFF_QF2  = OFF_QFB1 + 120;
constexpr size_t OFF_QFB2 = OFF_QF2 + 10080;
constexpr size_t OFF_QF3  = OFF_QFB2 + 84;
constexpr size_t OFF_OUT1 = OFF_QF3 + 756;                       // [256,6,79,79]
constexpr size_t OFF_OUT2 = OFF_OUT1 + (size_t)256*6*79*79;      // [256,12,38,38]
constexpr size_t OFF_OUT3 = OFF_OUT2 + (size_t)256*12*38*38;     // [256,18,18,18]
constexpr size_t OFF_OUT4 = OFF_OUT3 + (size_t)256*18*18*18;     // [256,18,8,8]
constexpr size_t OFF_OUT5 = OFF_OUT4 + (size_t)256*18*8*8;       // [256,162]
constexpr size_t OFF_FC1  = OFF_OUT5 + (size_t)256*162;          // [256,120]
constexpr size_t OFF_FC2  = OFF_FC1 + (size_t)256*120;           // [256,84]

// ---------------------------------------------------------------------------
// Weight + bias fake-quantization (one block per weight tensor)
//   s  = max|w| / 3 ; wq = clip(rint(w/s), -3, 3) * s
//   sb = s * (s_prev / 15) ; bq = rint(b/sb) * sb
// rintf = round-half-to-even, matching jnp.round.
// ---------------------------------------------------------------------------
__global__ void quant_prep(
    const float* w1, const float* w2, const float* b2,
    const float* w3, const float* b3, const float* w4, const float* b4,
    const float* w5, const float* b5, const float* fw1, const float* fb1,
    const float* fw2, const float* fb2, const float* fw3,
    const float* s1, const float* s2, const float* s3,
    const float* s4, const float* s5, const float* s6,
    float* ws)
{
    const int b = blockIdx.x;
    const float* W[8]  = {w1, w2, w3, w4, w5, fw1, fw2, fw3};
    const int    NW[8] = {162, 648, 1944, 2916, 2916, 19440, 10080, 756};
    float* WQ[8] = {ws+OFF_QW1, ws+OFF_QW2, ws+OFF_QW3, ws+OFF_QW4,
                    ws+OFF_QW5, ws+OFF_QF1, ws+OFF_QF2, ws+OFF_QF3};
    const float* B[8]  = {nullptr, b2, b3, b4, b5, fb1, fb2, nullptr};
    const int    NB[8] = {0, 12, 18, 18, 18, 120, 84, 0};
    float* BQ[8] = {nullptr, ws+OFF_QB2, ws+OFF_QB3, ws+OFF_QB4,
                    ws+OFF_QB5, ws+OFF_QFB1, ws+OFF_QFB2, nullptr};
    const float* SP[8] = {nullptr, s1, s2, s3, s4, s5, s6, nullptr};

    const float* w = W[b];
    const int nw = NW[b];

    // block max-abs reduction
    float mx = 0.0f;
    for (int i = threadIdx.x; i < nw; i += blockDim.x)
        mx = fmaxf(mx, fabsf(w[i]));
    __shared__ float red[256];
    red[threadIdx.x] = mx;
    __syncthreads();
    for (int s = 128; s > 0; s >>= 1) {
        if ((int)threadIdx.x < s)
            red[threadIdx.x] = fmaxf(red[threadIdx.x], red[threadIdx.x + s]);
        __syncthreads();
    }
    const float sw = red[0] / 3.0f;

    float* wq = WQ[b];
    for (int i = threadIdx.x; i < nw; i += blockDim.x) {
        float q = rintf(w[i] / sw);
        q = fminf(fmaxf(q, -3.0f), 3.0f);
        wq[i] = q * sw;
    }
    if (B[b] != nullptr) {
        const float sb = sw * (SP[b][0] / 15.0f);
        for (int i = threadIdx.x; i < NB[b]; i += blockDim.x)
            BQ[b][i] = rintf(B[b][i] / sb) * sb;
    }
}

// ---------------------------------------------------------------------------
// Fused conv3x3(VALID) [+bias] + quant_relu(s) + maxpool2
// Block = one (image, pooled-row). LDS holds 4 input rows of all CIN channels.
// Each thread computes pooled outputs: 2x2 conv window => 4x4 input window.
// quant_relu is monotone, so pool-then-quantize == quantize-then-pool.
// ---------------------------------------------------------------------------
template<int CIN, int COUT, int HIN, int WIN, int WPOOL, bool HAS_BIAS>
__global__ void conv_stage(const float* __restrict__ in,
                           const float* __restrict__ qw,
                           const float* __restrict__ qb,
                           const float* __restrict__ s_act,
                           float* __restrict__ out)
{
    const int r = blockIdx.x;          // pooled row
    const int n = blockIdx.y;          // image
    const int HPOOL = gridDim.x;

    __shared__ float lds[CIN][4][WIN];

    const float* inN = in + (size_t)n * CIN * HIN * WIN;
    const int total = CIN * 4 * WIN;
    for (int idx = threadIdx.x; idx < total; idx += blockDim.x) {
        const int c   = idx / (4 * WIN);
        const int rem = idx - c * (4 * WIN);
        const int rr  = rem / WIN;
        const int col = rem - rr * WIN;
        lds[c][rr][col] = inN[((size_t)c * HIN + (2 * r + rr)) * WIN + col];
    }
    __syncthreads();

    const float step = s_act[0] / 15.0f;

    for (int o = threadIdx.x; o < COUT * WPOOL; o += blockDim.x) {
        const int co = o / WPOOL;
        const int x  = o - co * WPOOL;

        float a00 = 0.f, a01 = 0.f, a10 = 0.f, a11 = 0.f;
        const float* wco = qw + co * CIN * 9;

        for (int c = 0; c < CIN; ++c) {
            float win[4][4];
#pragma unroll
            for (int rr = 0; rr < 4; ++rr)
#pragma unroll
                for (int cc = 0; cc < 4; ++cc)
                    win[rr][cc] = lds[c][rr][2 * x + cc];
#pragma unroll
            for (int kr = 0; kr < 3; ++kr)
#pragma unroll
                for (int kc = 0; kc < 3; ++kc) {
                    const float wv = wco[(c * 3 + kr) * 3 + kc];
                    a00 += win[kr    ][kc    ] * wv;
                    a01 += win[kr    ][kc + 1] * wv;
                    a10 += win[kr + 1][kc    ] * wv;
                    a11 += win[kr + 1][kc + 1] * wv;
                }
        }

        if (HAS_BIAS) {
            const float bias = qb[co];
            a00 += bias; a01 += bias; a10 += bias; a11 += bias;
        }

        const float m = fmaxf(fmaxf(a00, a01), fmaxf(a10, a11));
        const float v = fmaxf(m, 0.0f);
        float q = rintf(v / step);
        q = fminf(fmaxf(q, 0.0f), 15.0f);
        out[(((size_t)n * COUT + co) * HPOOL + r) * WPOOL + x] = q * step;
    }
}

// ---------------------------------------------------------------------------
// FC: out[n][m] = dot(in[n], w[m]) [+ bias] [quant_relu]
// ---------------------------------------------------------------------------
template<int K, int M, bool HAS_BIAS, bool DO_QUANT>
__global__ void fc_stage(const float* __restrict__ in,
                         const float* __restrict__ qw,
                         const float* __restrict__ qb,
                         const float* __restrict__ s_act,
                         float* __restrict__ out, int N)
{
    const int idx = blockIdx.x * blockDim.x + threadIdx.x;
    if (idx >= N * M) return;
    const int n = idx / M;
    const int m = idx - n * M;

    const float* irow = in + (size_t)n * K;
    const float* wrow = qw + (size_t)m * K;
    float acc = 0.0f;
    for (int k = 0; k < K; ++k)
        acc += irow[k] * wrow[k];

    if (HAS_BIAS) acc += qb[m];
    if (DO_QUANT) {
        const float step = s_act[0] / 15.0f;
        float q = rintf(fmaxf(acc, 0.0f) / step);
        q = fminf(fmaxf(q, 0.0f), 15.0f);
        acc = q * step;
    }
    out[idx] = acc;
}

// ---------------------------------------------------------------------------
extern "C" void kernel_launch(void* const* d_in, const int* in_sizes, int n_in,
                              void* d_out, int out_size, void* d_ws, size_t ws_size,
                              hipStream_t stream)
{
    const float* x   = (const float*)d_in[0];
    const float* w1  = (const float*)d_in[1];
    const float* w2  = (const float*)d_in[2];
    const float* b2  = (const float*)d_in[3];
    const float* w3  = (const float*)d_in[4];
    const float* b3  = (const float*)d_in[5];
    const float* w4  = (const float*)d_in[6];
    const float* b4  = (const float*)d_in[7];
    const float* w5  = (const float*)d_in[8];
    const float* b5  = (const float*)d_in[9];
    const float* fw1 = (const float*)d_in[10];
    const float* fb1 = (const float*)d_in[11];
    const float* fw2 = (const float*)d_in[12];
    const float* fb2 = (const float*)d_in[13];
    const float* fw3 = (const float*)d_in[14];
    const float* s1  = (const float*)d_in[15];
    const float* s2  = (const float*)d_in[16];
    const float* s3  = (const float*)d_in[17];
    const float* s4  = (const float*)d_in[18];
    const float* s5  = (const float*)d_in[19];
    const float* s6  = (const float*)d_in[20];
    const float* s7  = (const float*)d_in[21];

    float* ws = (float*)d_ws;
    float* out = (float*)d_out;

    // weight/bias fake-quant
    quant_prep<<<8, 256, 0, stream>>>(w1, w2, b2, w3, b3, w4, b4, w5, b5,
                                      fw1, fb1, fw2, fb2, fw3,
                                      s1, s2, s3, s4, s5, s6, ws);

    // stage 1: [256,3,160,160] -> [256,6,79,79]   (no bias)
    conv_stage<3, 6, 160, 160, 79, false>
        <<<dim3(79, 256), 256, 0, stream>>>(x, ws + OFF_QW1, nullptr, s1, ws + OFF_OUT1);

    // stage 2: -> [256,12,38,38]
    conv_stage<6, 12, 79, 79, 38, true>
        <<<dim3(38, 256), 256, 0, stream>>>(ws + OFF_OUT1, ws + OFF_QW2, ws + OFF_QB2, s2, ws + OFF_OUT2);

    // stage 3: -> [256,18,18,18]
    conv_stage<12, 18, 38, 38, 18, true>
        <<<dim3(18, 256), 256, 0, stream>>>(ws + OFF_OUT2, ws + OFF_QW3, ws + OFF_QB3, s3, ws + OFF_OUT3);

    // stage 4: -> [256,18,8,8]
    conv_stage<18, 18, 18, 18, 8, true>
        <<<dim3(8, 256), 192, 0, stream>>>(ws + OFF_OUT3, ws + OFF_QW4, ws + OFF_QB4, s4, ws + OFF_OUT4);

    // stage 5: -> [256,18,3,3] == [256,162]
    conv_stage<18, 18, 8, 8, 3, true>
        <<<dim3(3, 256), 64, 0, stream>>>(ws + OFF_OUT4, ws + OFF_QW5, ws + OFF_QB5, s5, ws + OFF_OUT5);

    // fc1: [256,162] -> [256,120]
    fc_stage<162, 120, true, true>
        <<<(256 * 120 + 255) / 256, 256, 0, stream>>>(ws + OFF_OUT5, ws + OFF_QF1, ws + OFF_QFB1, s6, ws + OFF_FC1, 256);

    // fc2: -> [256,84]
    fc_stage<120, 84, true, true>
        <<<(256 * 84 + 255) / 256, 256, 0, stream>>>(ws + OFF_FC1, ws + OFF_QF2, ws + OFF_QFB2, s7, ws + OFF_FC2, 256);

    // fc3: -> [256,9] (no bias, no quant)
    fc_stage<84, 9, false, false>
        <<<(256 * 9 + 255) / 256, 256, 0, stream>>>(ws + OFF_FC2, ws + OFF_QF3, nullptr, nullptr, out, 256);
}